// Round 15
// baseline (157.698 us; speedup 1.0000x reference)
//
#include <hip/hip_runtime.h>
#include <math.h>

#define KB_NUM 512
#define DIMC 64
#define BSZ 32
#define TLEN 4096
#define NTOK (BSZ * TLEN)          // 131072
#define DECAY_F 0.99f
#define EPS_F 1e-5f
#define NPART 256                  // partial buffers (one per bin block)

// output offsets (flat f32, reference return order)
#define Q_OFF    ((size_t)0)
#define IDX_OFF  ((size_t)BSZ * DIMC * TLEN)        // 8388608
#define LOSS_OFF (IDX_OFF + (size_t)NTOK)           // 8519680
#define PLEX_OFF (LOSS_OFF + 1)                     // 8519681
#define NEMB_OFF (PLEX_OFF + 1)                     // 8519682
#define NCS_OFF  (NEMB_OFF + (size_t)KB_NUM * DIMC) // 8552450
#define NEA_OFF  (NCS_OFF + (size_t)KB_NUM)         // 8552962

typedef _Float16 f16x8 __attribute__((ext_vector_type(8)));
typedef float    f32x4 __attribute__((ext_vector_type(4)));

// ---------------------------------------------------------------------------
// Kernel 0: prep embedding — f16 hi/lo split into FRAGMENT-MAJOR layout
// ---------------------------------------------------------------------------
__global__ __launch_bounds__(64) void vq_prep_e(
    const float* __restrict__ emb,
    _Float16* __restrict__ efrag,
    float* __restrict__ enorm)
{
    const int k = blockIdx.x;
    const int c = threadIdx.x;
    float v = emb[(size_t)k * DIMC + c];
    _Float16 h = (_Float16)v;
    _Float16 l = (_Float16)(v - (float)h);

    const int kgrp = k >> 4, row = k & 15;
    const int ks = c >> 5, seg = (c & 31) >> 3, j = c & 7;
    const int lane = seg * 16 + row;
    const size_t base = ((size_t)(kgrp * 2 + ks) * 2) * 512;
    efrag[base + (size_t)lane * 8 + j]       = h;   // hl = 0
    efrag[base + 512 + (size_t)lane * 8 + j] = l;   // hl = 1

    float s = v * v;
    #pragma unroll
    for (int off = 32; off > 0; off >>= 1)
        s += __shfl_down(s, off, 64);
    if (c == 0) enorm[k] = 0.5f * s;
}

// load one kgrp's 4 fragment vectors (wraps at 32 -> harmless valid loads)
#define LOADA(P, kg) do {                                                     \
    const _Float16* fb_ = efrag + ((size_t)((kg) & 31) * 4) * 512             \
                                + (size_t)ln * 8;                             \
    P##h0 = *(const f16x8*)(fb_);                                             \
    P##l0 = *(const f16x8*)(fb_ + 512);                                       \
    P##h1 = *(const f16x8*)(fb_ + 1024);                                      \
    P##l1 = *(const f16x8*)(fb_ + 1536);                                      \
} while (0)

// consume buffer P into acc[ct][*]; MFMA order identical to rounds 6-14
#define CONSUME(P, ct) do {                                                   \
    _Pragma("unroll")                                                         \
    for (int tt = 0; tt < 4; ++tt)                                            \
        acc[ct][tt] = __builtin_amdgcn_mfma_f32_16x16x32_f16(                 \
            P##h0, zhf[tt][0], acc[ct][tt], 0, 0, 0);                         \
    _Pragma("unroll")                                                         \
    for (int tt = 0; tt < 4; ++tt)                                            \
        acc[ct][tt] = __builtin_amdgcn_mfma_f32_16x16x32_f16(                 \
            P##h0, zlf[tt][0], acc[ct][tt], 0, 0, 0);                         \
    _Pragma("unroll")                                                         \
    for (int tt = 0; tt < 4; ++tt)                                            \
        acc[ct][tt] = __builtin_amdgcn_mfma_f32_16x16x32_f16(                 \
            P##l0, zhf[tt][0], acc[ct][tt], 0, 0, 0);                         \
    _Pragma("unroll")                                                         \
    for (int tt = 0; tt < 4; ++tt)                                            \
        acc[ct][tt] = __builtin_amdgcn_mfma_f32_16x16x32_f16(                 \
            P##l0, zlf[tt][0], acc[ct][tt], 0, 0, 0);                         \
    _Pragma("unroll")                                                         \
    for (int tt = 0; tt < 4; ++tt)                                            \
        acc[ct][tt] = __builtin_amdgcn_mfma_f32_16x16x32_f16(                 \
            P##h1, zhf[tt][1], acc[ct][tt], 0, 0, 0);                         \
    _Pragma("unroll")                                                         \
    for (int tt = 0; tt < 4; ++tt)                                            \
        acc[ct][tt] = __builtin_amdgcn_mfma_f32_16x16x32_f16(                 \
            P##h1, zlf[tt][1], acc[ct][tt], 0, 0, 0);                         \
    _Pragma("unroll")                                                         \
    for (int tt = 0; tt < 4; ++tt)                                            \
        acc[ct][tt] = __builtin_amdgcn_mfma_f32_16x16x32_f16(                 \
            P##l1, zhf[tt][1], acc[ct][tt], 0, 0, 0);                         \
    _Pragma("unroll")                                                         \
    for (int tt = 0; tt < 4; ++tt)                                            \
        acc[ct][tt] = __builtin_amdgcn_mfma_f32_16x16x32_f16(                 \
            P##l1, zlf[tt][1], acc[ct][tt], 0, 0, 0);                         \
} while (0)

// ---------------------------------------------------------------------------
// Kernel 1: MFMA argmin + quantize + loss  (round-13 main, zt removed)
// block = 256 thr = 4 waves; tile = 256 tokens x 512 codes (full K).
// ---------------------------------------------------------------------------
__global__ __launch_bounds__(256, 2) void vq_main_kernel(
    const float* __restrict__ z,
    const float* __restrict__ emb,
    const _Float16* __restrict__ efrag,
    const float* __restrict__ enorm,
    float* __restrict__ out,
    float* __restrict__ lossAcc)
{
    __shared__ float zs[256 * 65];   // [token][ch], pad 65 -> conflict-free
    __shared__ float sen[KB_NUM];    // 2 KB enorm table (fold reads LDS)

    const int tid = threadIdx.x;
    const int w   = tid >> 6;
    const int ln  = tid & 63;
    const int bk  = blockIdx.x;
    const int b   = bk >> 4;               // 16 blocks per batch row
    const int t0  = (bk & 15) << 8;        // 256 tokens per block

    sen[tid]       = enorm[tid];
    sen[tid + 256] = enorm[tid + 256];

    const float* zg = z + (size_t)b * (DIMC * TLEN) + t0;

    // stage: transpose z[c][t] -> zs[t][c]; coalesced global, conflict-free LDS
    #pragma unroll 8
    for (int c = 0; c < DIMC; ++c)
        zs[tid * 65 + c] = zg[(size_t)c * TLEN + tid];
    __syncthreads();

    // build B fragments once (held in VGPRs for the whole K-loop)
    f16x8 zhf[4][2], zlf[4][2];
    #pragma unroll
    for (int tt = 0; tt < 4; ++tt) {
        #pragma unroll
        for (int ks = 0; ks < 2; ++ks) {
            const float* zrow = &zs[(w * 64 + tt * 16 + (ln & 15)) * 65
                                    + ks * 32 + ((ln >> 4) << 3)];
            #pragma unroll
            for (int j = 0; j < 8; ++j) {
                float v = zrow[j];
                _Float16 h = (_Float16)v;
                zhf[tt][ks][j] = h;
                zlf[tt][ks][j] = (_Float16)(v - (float)h);
            }
        }
    }

    float bv[4] = {3.4e38f, 3.4e38f, 3.4e38f, 3.4e38f};
    int   bi[4] = {0, 0, 0, 0};

    // A-operand double buffer (static names, depth 2, distance 2)
    f16x8 A0h0, A0l0, A0h1, A0l1;
    f16x8 A1h0, A1l0, A1h1, A1l1;
    LOADA(A0, 0);
    LOADA(A1, 1);

    #pragma unroll 1
    for (int chunk = 0; chunk < 8; ++chunk) {        // 64 codes per chunk
        const int kb = chunk * 4;
        f32x4 acc[4][4];
        #pragma unroll
        for (int ct = 0; ct < 4; ++ct)
            #pragma unroll
            for (int tt = 0; tt < 4; ++tt)
                acc[ct][tt] = (f32x4){0.f, 0.f, 0.f, 0.f};

        CONSUME(A0, 0); LOADA(A0, kb + 2);
        CONSUME(A1, 1); LOADA(A1, kb + 3);
        CONSUME(A0, 2); LOADA(A0, kb + 4);   // next chunk's kgrp 0
        CONSUME(A1, 3); LOADA(A1, kb + 5);   // next chunk's kgrp 1

        // fold: s = 0.5||e||^2 - z.e ; ascending code order (chunk, ct, reg)
        #pragma unroll
        for (int ct = 0; ct < 4; ++ct) {
            const int cb = chunk * 64 + ct * 16 + ((ln >> 4) << 2);
            float4 en = *(const float4*)&sen[cb];
            const float e0 = en.x, e1 = en.y, e2 = en.z, e3 = en.w;
            #pragma unroll
            for (int tt = 0; tt < 4; ++tt) {
                float s0 = e0 - acc[ct][tt][0];
                float s1 = e1 - acc[ct][tt][1];
                float s2 = e2 - acc[ct][tt][2];
                float s3 = e3 - acc[ct][tt][3];
                if (s0 < bv[tt]) { bv[tt] = s0; bi[tt] = cb; }
                if (s1 < bv[tt]) { bv[tt] = s1; bi[tt] = cb + 1; }
                if (s2 < bv[tt]) { bv[tt] = s2; bi[tt] = cb + 2; }
                if (s3 < bv[tt]) { bv[tt] = s3; bi[tt] = cb + 3; }
            }
        }
    }

    // cross-lane fold over the 4 row-groups (lane>>4); lower index wins ties
    #pragma unroll
    for (int mask = 16; mask <= 32; mask <<= 1) {
        #pragma unroll
        for (int tt = 0; tt < 4; ++tt) {
            float ov = __shfl_xor(bv[tt], mask, 64);
            int   oi = __shfl_xor(bi[tt], mask, 64);
            if (ov < bv[tt] || (ov == bv[tt] && oi < bi[tt])) {
                bv[tt] = ov; bi[tt] = oi;
            }
        }
    }

    // epilogue: lane ln owns token w*64 + ln
    const int g = ln >> 4;
    const int idxv = (g == 0) ? bi[0] : (g == 1) ? bi[1] : (g == 2) ? bi[2] : bi[3];
    const int tok = w * 64 + ln;

    out[IDX_OFF + (size_t)b * TLEN + t0 + tok] = (float)idxv;

    const float* er   = emb + (size_t)idxv * DIMC;   // fp32 codebook row
    const float* zrow = &zs[tok * 65];
    float* qo = out + (size_t)b * (DIMC * TLEN) + t0 + tok;

    float lsum = 0.f;
    #pragma unroll
    for (int c4 = 0; c4 < DIMC / 4; ++c4) {
        float4 ev = *(const float4*)(er + c4 * 4);
        float z0 = zrow[c4 * 4 + 0], z1 = zrow[c4 * 4 + 1];
        float z2 = zrow[c4 * 4 + 2], z3 = zrow[c4 * 4 + 3];
        float d0 = ev.x - z0, d1 = ev.y - z1, d2 = ev.z - z2, d3 = ev.w - z3;
        qo[(size_t)(c4 * 4 + 0) * TLEN] = z0 + d0;   // z + (q - z), ref rounding
        qo[(size_t)(c4 * 4 + 1) * TLEN] = z1 + d1;
        qo[(size_t)(c4 * 4 + 2) * TLEN] = z2 + d2;
        qo[(size_t)(c4 * 4 + 3) * TLEN] = z3 + d3;
        lsum = fmaf(d0, d0, lsum); lsum = fmaf(d1, d1, lsum);
        lsum = fmaf(d2, d2, lsum); lsum = fmaf(d3, d3, lsum);
    }

    #pragma unroll
    for (int off = 32; off > 0; off >>= 1)
        lsum += __shfl_down(lsum, off, 64);
    if (ln == 0) atomicAdd(lossAcc, lsum);
}

// ---------------------------------------------------------------------------
// Kernel 2: segment-sum binning — NO global atomics (partial per block).
// grid = 256 blocks x 512 thr; thread = 1 token (its own idx, no shfl).
// Accumulate: accT[c][idx] — bank (c*513+idx)%32 rotates with c, random idx
// -> ~2-way (free). z read c-major: fixed c, 512 consecutive t = coalesced.
// Flush: PLAIN stores of the whole 128KB partial (no RMW). ATOMICFLUSH=true
// variant only for the small-ws fallback (P=1).
// ---------------------------------------------------------------------------
template <bool ATOMICFLUSH>
__global__ __launch_bounds__(512, 1) void vq_bin_kernel(
    const float* __restrict__ z,
    const float* __restrict__ out,    // reads idx at IDX_OFF
    float* __restrict__ pcnt,         // [P][KB_NUM]
    float* __restrict__ pesum)        // [P][KB_NUM*DIMC] (k-major [k][c])
{
    __shared__ float accT[DIMC][KB_NUM + 1];   // 131.3 KB transposed acc
    __shared__ float scnt[KB_NUM];

    const int tid = threadIdx.x;
    for (int j = tid; j < DIMC * (KB_NUM + 1); j += 512) ((float*)accT)[j] = 0.f;
    scnt[tid] = 0.f;                            // 512 threads = KB_NUM
    __syncthreads();

    const int b  = blockIdx.x >> 3;             // 8 blocks per batch row
    const int tb = (blockIdx.x & 7) * 512;      // token base within row
    const int myidx = (int)out[IDX_OFF + (size_t)b * TLEN + tb + tid];
    atomicAdd(&scnt[myidx], 1.0f);

    const float* zp = z + (size_t)b * (DIMC * TLEN) + tb;
    #pragma unroll 8
    for (int c = 0; c < DIMC; ++c) {
        float v = zp[(size_t)c * TLEN + tid];   // 2KB coalesced per instr
        atomicAdd(&accT[c][myidx], v);          // random-bank ~2-way, free
    }
    __syncthreads();

    // flush: accT[c][k] -> pesum[blk][k*64+c]; LDS read bank (c+k)%32 ->
    // conflict-free; global stores contiguous.
    float* pe = pesum + (size_t)blockIdx.x * (KB_NUM * DIMC);
    for (int j = tid; j < KB_NUM * DIMC; j += 512) {
        const int k = j >> 6, c = j & 63;
        float v = accT[c][k];
        if (ATOMICFLUSH) { if (v != 0.f) atomicAdd(pe + j, v); }
        else             pe[j] = v;
    }
    if (ATOMICFLUSH) {
        float v = scnt[tid];
        if (v != 0.f) atomicAdd(pcnt + tid, v);
    } else {
        pcnt[(size_t)blockIdx.x * KB_NUM + tid] = scnt[tid];
    }
}

// ---------------------------------------------------------------------------
// Kernel 3: stats — new_cluster_size, n_tot, perplexity, loss
// ---------------------------------------------------------------------------
__global__ __launch_bounds__(512) void vq_stats_kernel(
    const float* __restrict__ cluster_size,
    const float* __restrict__ pcnt,
    const float* __restrict__ lossAcc,
    float* __restrict__ out,
    float* __restrict__ ntotp,
    int P)
{
    const int k = threadIdx.x;

    float n = 0.f;
    #pragma unroll 8
    for (int p = 0; p < P; ++p) n += pcnt[(size_t)p * KB_NUM + k];

    float ncs = cluster_size[k] * DECAY_F + (1.0f - DECAY_F) * n;
    out[NCS_OFF + k] = ncs;

    __shared__ float red[KB_NUM];

    red[k] = ncs;
    __syncthreads();
    for (int s = KB_NUM / 2; s > 0; s >>= 1) {
        if (k < s) red[k] += red[k + s];
        __syncthreads();
    }
    if (k == 0) ntotp[0] = red[0];
    __syncthreads();

    float p = n * (1.0f / (float)NTOK);
    red[k] = p * logf(p + 1e-10f);
    __syncthreads();
    for (int s = KB_NUM / 2; s > 0; s >>= 1) {
        if (k < s) red[k] += red[k + s];
        __syncthreads();
    }
    if (k == 0) {
        out[PLEX_OFF] = expf(-red[0]);
        out[LOSS_OFF] = 0.25f * lossAcc[0] * (1.0f / (float)(BSZ * DIMC * TLEN));
    }
}

// ---------------------------------------------------------------------------
// Kernel 4: embedding update — 512 blocks (k) x 64 threads (c);
// sums P partials with coalesced 256B reads, unroll 16 for ILP.
// ---------------------------------------------------------------------------
__global__ __launch_bounds__(64) void vq_embed_kernel(
    const float* __restrict__ embed_avg,
    const float* __restrict__ pesum,
    const float* __restrict__ ntotp,
    float* __restrict__ out,
    int P)
{
    const int k = blockIdx.x;
    const int c = threadIdx.x;

    float es = 0.f;
    #pragma unroll 16
    for (int p = 0; p < P; ++p)
        es += pesum[(size_t)p * (KB_NUM * DIMC) + (size_t)k * DIMC + c];

    float nea = embed_avg[(size_t)k * DIMC + c] * DECAY_F + (1.0f - DECAY_F) * es;
    out[NEA_OFF + (size_t)k * DIMC + c] = nea;

    float ncs  = out[NCS_OFF + k];
    float ntot = ntotp[0];
    float denom = (ncs + EPS_F) / (ntot + (float)KB_NUM * EPS_F) * ntot;
    out[NEMB_OFF + (size_t)k * DIMC + c] = nea / denom;
}

// ---------------------------------------------------------------------------
extern "C" void kernel_launch(void* const* d_in, const int* in_sizes, int n_in,
                              void* d_out, int out_size, void* d_ws, size_t ws_size,
                              hipStream_t stream)
{
    const float* z            = (const float*)d_in[0];
    const float* emb          = (const float*)d_in[1];
    const float* cluster_size = (const float*)d_in[2];
    const float* embed_avg    = (const float*)d_in[3];
    float* out = (float*)d_out;

    char* ws = (char*)d_ws;
    float*     lossAcc = (float*)ws;                 // 1 f32
    float*     ntotp   = (float*)(ws + 64);          // 1 f32
    float*     enorm   = (float*)(ws + 256);         // 512 f32
    _Float16*  efrag   = (_Float16*)(ws + 4096);     // 128 KB
    const size_t PART_OFF   = 4096 + 131072;         // 135168
    const size_t pcnt_bytes  = (size_t)NPART * KB_NUM * sizeof(float);        // 512 KB
    const size_t pesum_bytes = (size_t)NPART * KB_NUM * DIMC * sizeof(float); // 32 MB
    const size_t need = PART_OFF + pcnt_bytes + pesum_bytes;   // ~32.7 MB

    int P;
    float *pcnt, *pesum;
    if (ws_size >= need) {
        P = NPART;
        pcnt  = (float*)(ws + PART_OFF);
        pesum = (float*)(ws + PART_OFF + pcnt_bytes);
        // partials fully overwritten by bin -> only zero the header
        hipMemsetAsync(ws, 0, 4096, stream);
    } else {
        P = 1;
        pcnt  = (float*)(ws + PART_OFF);
        pesum = (float*)(ws + PART_OFF + KB_NUM * sizeof(float));
        hipMemsetAsync(ws, 0, PART_OFF + (KB_NUM + KB_NUM * DIMC) * sizeof(float),
                       stream);
    }

    vq_prep_e<<<dim3(KB_NUM), dim3(DIMC), 0, stream>>>(emb, efrag, enorm);

    vq_main_kernel<<<dim3(NTOK / 256), dim3(256), 0, stream>>>(
        z, emb, efrag, enorm, out, lossAcc);

    if (P == NPART)
        vq_bin_kernel<false><<<dim3(NTOK / 512), dim3(512), 0, stream>>>(
            z, out, pcnt, pesum);
    else
        vq_bin_kernel<true><<<dim3(NTOK / 512), dim3(512), 0, stream>>>(
            z, out, pcnt, pesum);

    vq_stats_kernel<<<dim3(1), dim3(512), 0, stream>>>(
        cluster_size, pcnt, lossAcc, out, ntotp, P);

    vq_embed_kernel<<<dim3(KB_NUM), dim3(DIMC), 0, stream>>>(
        embed_avg, pesum, ntotp, out, P);
}

// Round 16
// 151.909 us; speedup vs baseline: 1.0381x; 1.0381x over previous
//
#include <hip/hip_runtime.h>
#include <math.h>

#define KB_NUM 512
#define DIMC 64
#define BSZ 32
#define TLEN 4096
#define NTOK (BSZ * TLEN)          // 131072
#define DECAY_F 0.99f
#define EPS_F 1e-5f
#define NPART 256                  // partial buffers (one per bin block)

// output offsets (flat f32, reference return order)
#define Q_OFF    ((size_t)0)
#define IDX_OFF  ((size_t)BSZ * DIMC * TLEN)        // 8388608
#define LOSS_OFF (IDX_OFF + (size_t)NTOK)           // 8519680
#define PLEX_OFF (LOSS_OFF + 1)                     // 8519681
#define NEMB_OFF (PLEX_OFF + 1)                     // 8519682
#define NCS_OFF  (NEMB_OFF + (size_t)KB_NUM * DIMC) // 8552450
#define NEA_OFF  (NCS_OFF + (size_t)KB_NUM)         // 8552962

typedef _Float16 f16x8 __attribute__((ext_vector_type(8)));
typedef float    f32x4 __attribute__((ext_vector_type(4)));

// ---------------------------------------------------------------------------
// Kernel 0: prep embedding — f16 hi/lo split into FRAGMENT-MAJOR layout
// ---------------------------------------------------------------------------
__global__ __launch_bounds__(64) void vq_prep_e(
    const float* __restrict__ emb,
    _Float16* __restrict__ efrag,
    float* __restrict__ enorm)
{
    const int k = blockIdx.x;
    const int c = threadIdx.x;
    float v = emb[(size_t)k * DIMC + c];
    _Float16 h = (_Float16)v;
    _Float16 l = (_Float16)(v - (float)h);

    const int kgrp = k >> 4, row = k & 15;
    const int ks = c >> 5, seg = (c & 31) >> 3, j = c & 7;
    const int lane = seg * 16 + row;
    const size_t base = ((size_t)(kgrp * 2 + ks) * 2) * 512;
    efrag[base + (size_t)lane * 8 + j]       = h;   // hl = 0
    efrag[base + 512 + (size_t)lane * 8 + j] = l;   // hl = 1

    float s = v * v;
    #pragma unroll
    for (int off = 32; off > 0; off >>= 1)
        s += __shfl_down(s, off, 64);
    if (c == 0) enorm[k] = 0.5f * s;
}

// load one kgrp's 4 fragment vectors (wraps at 32 -> harmless valid loads)
#define LOADA(P, kg) do {                                                     \
    const _Float16* fb_ = efrag + ((size_t)((kg) & 31) * 4) * 512             \
                                + (size_t)ln * 8;                             \
    P##h0 = *(const f16x8*)(fb_);                                             \
    P##l0 = *(const f16x8*)(fb_ + 512);                                       \
    P##h1 = *(const f16x8*)(fb_ + 1024);                                      \
    P##l1 = *(const f16x8*)(fb_ + 1536);                                      \
} while (0)

// consume buffer P into acc[ct][*]; MFMA order identical to rounds 6-15
#define CONSUME(P, ct) do {                                                   \
    _Pragma("unroll")                                                         \
    for (int tt = 0; tt < 4; ++tt)                                            \
        acc[ct][tt] = __builtin_amdgcn_mfma_f32_16x16x32_f16(                 \
            P##h0, zhf[tt][0], acc[ct][tt], 0, 0, 0);                         \
    _Pragma("unroll")                                                         \
    for (int tt = 0; tt < 4; ++tt)                                            \
        acc[ct][tt] = __builtin_amdgcn_mfma_f32_16x16x32_f16(                 \
            P##h0, zlf[tt][0], acc[ct][tt], 0, 0, 0);                         \
    _Pragma("unroll")                                                         \
    for (int tt = 0; tt < 4; ++tt)                                            \
        acc[ct][tt] = __builtin_amdgcn_mfma_f32_16x16x32_f16(                 \
            P##l0, zhf[tt][0], acc[ct][tt], 0, 0, 0);                         \
    _Pragma("unroll")                                                         \
    for (int tt = 0; tt < 4; ++tt)                                            \
        acc[ct][tt] = __builtin_amdgcn_mfma_f32_16x16x32_f16(                 \
            P##l0, zlf[tt][0], acc[ct][tt], 0, 0, 0);                         \
    _Pragma("unroll")                                                         \
    for (int tt = 0; tt < 4; ++tt)                                            \
        acc[ct][tt] = __builtin_amdgcn_mfma_f32_16x16x32_f16(                 \
            P##h1, zhf[tt][1], acc[ct][tt], 0, 0, 0);                         \
    _Pragma("unroll")                                                         \
    for (int tt = 0; tt < 4; ++tt)                                            \
        acc[ct][tt] = __builtin_amdgcn_mfma_f32_16x16x32_f16(                 \
            P##h1, zlf[tt][1], acc[ct][tt], 0, 0, 0);                         \
    _Pragma("unroll")                                                         \
    for (int tt = 0; tt < 4; ++tt)                                            \
        acc[ct][tt] = __builtin_amdgcn_mfma_f32_16x16x32_f16(                 \
            P##l1, zhf[tt][1], acc[ct][tt], 0, 0, 0);                         \
    _Pragma("unroll")                                                         \
    for (int tt = 0; tt < 4; ++tt)                                            \
        acc[ct][tt] = __builtin_amdgcn_mfma_f32_16x16x32_f16(                 \
            P##l1, zlf[tt][1], acc[ct][tt], 0, 0, 0);                         \
} while (0)

// ---------------------------------------------------------------------------
// Kernel 1: MFMA argmin + quantize + loss  (unchanged from round 15)
// ---------------------------------------------------------------------------
__global__ __launch_bounds__(256, 2) void vq_main_kernel(
    const float* __restrict__ z,
    const float* __restrict__ emb,
    const _Float16* __restrict__ efrag,
    const float* __restrict__ enorm,
    float* __restrict__ out,
    float* __restrict__ lossAcc)
{
    __shared__ float zs[256 * 65];   // [token][ch], pad 65 -> conflict-free
    __shared__ float sen[KB_NUM];    // 2 KB enorm table (fold reads LDS)

    const int tid = threadIdx.x;
    const int w   = tid >> 6;
    const int ln  = tid & 63;
    const int bk  = blockIdx.x;
    const int b   = bk >> 4;               // 16 blocks per batch row
    const int t0  = (bk & 15) << 8;        // 256 tokens per block

    sen[tid]       = enorm[tid];
    sen[tid + 256] = enorm[tid + 256];

    const float* zg = z + (size_t)b * (DIMC * TLEN) + t0;

    // stage: transpose z[c][t] -> zs[t][c]; coalesced global, conflict-free LDS
    #pragma unroll 8
    for (int c = 0; c < DIMC; ++c)
        zs[tid * 65 + c] = zg[(size_t)c * TLEN + tid];
    __syncthreads();

    // build B fragments once (held in VGPRs for the whole K-loop)
    f16x8 zhf[4][2], zlf[4][2];
    #pragma unroll
    for (int tt = 0; tt < 4; ++tt) {
        #pragma unroll
        for (int ks = 0; ks < 2; ++ks) {
            const float* zrow = &zs[(w * 64 + tt * 16 + (ln & 15)) * 65
                                    + ks * 32 + ((ln >> 4) << 3)];
            #pragma unroll
            for (int j = 0; j < 8; ++j) {
                float v = zrow[j];
                _Float16 h = (_Float16)v;
                zhf[tt][ks][j] = h;
                zlf[tt][ks][j] = (_Float16)(v - (float)h);
            }
        }
    }

    float bv[4] = {3.4e38f, 3.4e38f, 3.4e38f, 3.4e38f};
    int   bi[4] = {0, 0, 0, 0};

    // A-operand double buffer (static names, depth 2, distance 2)
    f16x8 A0h0, A0l0, A0h1, A0l1;
    f16x8 A1h0, A1l0, A1h1, A1l1;
    LOADA(A0, 0);
    LOADA(A1, 1);

    #pragma unroll 1
    for (int chunk = 0; chunk < 8; ++chunk) {        // 64 codes per chunk
        const int kb = chunk * 4;
        f32x4 acc[4][4];
        #pragma unroll
        for (int ct = 0; ct < 4; ++ct)
            #pragma unroll
            for (int tt = 0; tt < 4; ++tt)
                acc[ct][tt] = (f32x4){0.f, 0.f, 0.f, 0.f};

        CONSUME(A0, 0); LOADA(A0, kb + 2);
        CONSUME(A1, 1); LOADA(A1, kb + 3);
        CONSUME(A0, 2); LOADA(A0, kb + 4);   // next chunk's kgrp 0
        CONSUME(A1, 3); LOADA(A1, kb + 5);   // next chunk's kgrp 1

        // fold: s = 0.5||e||^2 - z.e ; ascending code order (chunk, ct, reg)
        #pragma unroll
        for (int ct = 0; ct < 4; ++ct) {
            const int cb = chunk * 64 + ct * 16 + ((ln >> 4) << 2);
            float4 en = *(const float4*)&sen[cb];
            const float e0 = en.x, e1 = en.y, e2 = en.z, e3 = en.w;
            #pragma unroll
            for (int tt = 0; tt < 4; ++tt) {
                float s0 = e0 - acc[ct][tt][0];
                float s1 = e1 - acc[ct][tt][1];
                float s2 = e2 - acc[ct][tt][2];
                float s3 = e3 - acc[ct][tt][3];
                if (s0 < bv[tt]) { bv[tt] = s0; bi[tt] = cb; }
                if (s1 < bv[tt]) { bv[tt] = s1; bi[tt] = cb + 1; }
                if (s2 < bv[tt]) { bv[tt] = s2; bi[tt] = cb + 2; }
                if (s3 < bv[tt]) { bv[tt] = s3; bi[tt] = cb + 3; }
            }
        }
    }

    // cross-lane fold over the 4 row-groups (lane>>4); lower index wins ties
    #pragma unroll
    for (int mask = 16; mask <= 32; mask <<= 1) {
        #pragma unroll
        for (int tt = 0; tt < 4; ++tt) {
            float ov = __shfl_xor(bv[tt], mask, 64);
            int   oi = __shfl_xor(bi[tt], mask, 64);
            if (ov < bv[tt] || (ov == bv[tt] && oi < bi[tt])) {
                bv[tt] = ov; bi[tt] = oi;
            }
        }
    }

    // epilogue: lane ln owns token w*64 + ln
    const int g = ln >> 4;
    const int idxv = (g == 0) ? bi[0] : (g == 1) ? bi[1] : (g == 2) ? bi[2] : bi[3];
    const int tok = w * 64 + ln;

    out[IDX_OFF + (size_t)b * TLEN + t0 + tok] = (float)idxv;

    const float* er   = emb + (size_t)idxv * DIMC;   // fp32 codebook row
    const float* zrow = &zs[tok * 65];
    float* qo = out + (size_t)b * (DIMC * TLEN) + t0 + tok;

    float lsum = 0.f;
    #pragma unroll
    for (int c4 = 0; c4 < DIMC / 4; ++c4) {
        float4 ev = *(const float4*)(er + c4 * 4);
        float z0 = zrow[c4 * 4 + 0], z1 = zrow[c4 * 4 + 1];
        float z2 = zrow[c4 * 4 + 2], z3 = zrow[c4 * 4 + 3];
        float d0 = ev.x - z0, d1 = ev.y - z1, d2 = ev.z - z2, d3 = ev.w - z3;
        qo[(size_t)(c4 * 4 + 0) * TLEN] = z0 + d0;   // z + (q - z), ref rounding
        qo[(size_t)(c4 * 4 + 1) * TLEN] = z1 + d1;
        qo[(size_t)(c4 * 4 + 2) * TLEN] = z2 + d2;
        qo[(size_t)(c4 * 4 + 3) * TLEN] = z3 + d3;
        lsum = fmaf(d0, d0, lsum); lsum = fmaf(d1, d1, lsum);
        lsum = fmaf(d2, d2, lsum); lsum = fmaf(d3, d3, lsum);
    }

    #pragma unroll
    for (int off = 32; off > 0; off >>= 1)
        lsum += __shfl_down(lsum, off, 64);
    if (ln == 0) atomicAdd(lossAcc, lsum);
}

// ---------------------------------------------------------------------------
// Kernel 2: segment-sum binning — partial per block (unchanged from round 15)
// ---------------------------------------------------------------------------
template <bool ATOMICFLUSH>
__global__ __launch_bounds__(512, 1) void vq_bin_kernel(
    const float* __restrict__ z,
    const float* __restrict__ out,    // reads idx at IDX_OFF
    float* __restrict__ pcnt,         // [P][KB_NUM]
    float* __restrict__ pesum)        // [P][KB_NUM*DIMC] (k-major [k][c])
{
    __shared__ float accT[DIMC][KB_NUM + 1];   // 131.3 KB transposed acc
    __shared__ float scnt[KB_NUM];

    const int tid = threadIdx.x;
    for (int j = tid; j < DIMC * (KB_NUM + 1); j += 512) ((float*)accT)[j] = 0.f;
    scnt[tid] = 0.f;                            // 512 threads = KB_NUM
    __syncthreads();

    const int b  = blockIdx.x >> 3;             // 8 blocks per batch row
    const int tb = (blockIdx.x & 7) * 512;      // token base within row
    const int myidx = (int)out[IDX_OFF + (size_t)b * TLEN + tb + tid];
    atomicAdd(&scnt[myidx], 1.0f);

    const float* zp = z + (size_t)b * (DIMC * TLEN) + tb;
    #pragma unroll 8
    for (int c = 0; c < DIMC; ++c) {
        float v = zp[(size_t)c * TLEN + tid];   // 2KB coalesced per instr
        atomicAdd(&accT[c][myidx], v);          // random-bank ~2-way, free
    }
    __syncthreads();

    // flush: accT[c][k] -> pesum[blk][k*64+c]; LDS read bank (c+k)%32 ->
    // conflict-free; global stores contiguous.
    float* pe = pesum + (size_t)blockIdx.x * (KB_NUM * DIMC);
    for (int j = tid; j < KB_NUM * DIMC; j += 512) {
        const int k = j >> 6, c = j & 63;
        float v = accT[c][k];
        if (ATOMICFLUSH) { if (v != 0.f) atomicAdd(pe + j, v); }
        else             pe[j] = v;
    }
    if (ATOMICFLUSH) {
        float v = scnt[tid];
        if (v != 0.f) atomicAdd(pcnt + tid, v);
    } else {
        pcnt[(size_t)blockIdx.x * KB_NUM + tid] = scnt[tid];
    }
}

// ---------------------------------------------------------------------------
// Kernel 3: stats — RESHAPED pcnt reduce: 4 p-groups x 128 float4-k lanes,
// coalesced 2KB reads per group-step; combine via LDS part[4][512].
// Count sums are exact integers in fp32 -> reassociation is exact.
// ---------------------------------------------------------------------------
__global__ __launch_bounds__(512) void vq_stats_kernel(
    const float* __restrict__ cluster_size,
    const float* __restrict__ pcnt,
    const float* __restrict__ lossAcc,
    float* __restrict__ out,
    float* __restrict__ ntotp,
    int P)
{
    __shared__ float part[4][KB_NUM];   // 8 KB
    __shared__ float red[KB_NUM];

    const int tid = threadIdx.x;
    const int pg  = tid >> 7;           // 4 p-groups
    const int kq  = tid & 127;          // float4 index over k

    {
        const int pcount = (P + 3) / 4;            // per-group share (P mult of 4 or 1)
        const int p0 = pg * pcount;
        float4 a = {0.f, 0.f, 0.f, 0.f};
        for (int p = p0; p < p0 + pcount && p < P; ++p) {
            float4 v = *(const float4*)(pcnt + (size_t)p * KB_NUM + kq * 4);
            a.x += v.x; a.y += v.y; a.z += v.z; a.w += v.w;
        }
        part[pg][kq * 4 + 0] = a.x;
        part[pg][kq * 4 + 1] = a.y;
        part[pg][kq * 4 + 2] = a.z;
        part[pg][kq * 4 + 3] = a.w;
    }
    __syncthreads();

    const int k = tid;
    float n = part[0][k] + part[1][k] + part[2][k] + part[3][k];

    float ncs = cluster_size[k] * DECAY_F + (1.0f - DECAY_F) * n;
    out[NCS_OFF + k] = ncs;

    red[k] = ncs;
    __syncthreads();
    for (int s = KB_NUM / 2; s > 0; s >>= 1) {
        if (k < s) red[k] += red[k + s];
        __syncthreads();
    }
    if (k == 0) ntotp[0] = red[0];
    __syncthreads();

    float p = n * (1.0f / (float)NTOK);
    red[k] = p * logf(p + 1e-10f);
    __syncthreads();
    for (int s = KB_NUM / 2; s > 0; s >>= 1) {
        if (k < s) red[k] += red[k + s];
        __syncthreads();
    }
    if (k == 0) {
        out[PLEX_OFF] = expf(-red[0]);
        out[LOSS_OFF] = 0.25f * lossAcc[0] * (1.0f / (float)(BSZ * DIMC * TLEN));
    }
}

// ---------------------------------------------------------------------------
// Kernel 4: embedding update — RESHAPED: grid 128 x 256; thread = flat (k,c);
// consecutive threads -> consecutive addresses (coalesced 1KB/wave per p);
// 4 independent accumulators break the fp-add chain; unroll 4 -> 16 loads
// in flight per thread.
// ---------------------------------------------------------------------------
__global__ __launch_bounds__(256) void vq_embed_kernel(
    const float* __restrict__ embed_avg,
    const float* __restrict__ pesum,
    const float* __restrict__ ntotp,
    float* __restrict__ out,
    int P)
{
    const int j = blockIdx.x * 256 + threadIdx.x;   // 0..32767 = k*64+c
    const int k = j >> 6;

    float e0 = 0.f, e1 = 0.f, e2 = 0.f, e3 = 0.f;
    int p = 0;
    #pragma unroll 4
    for (; p + 4 <= P; p += 4) {
        e0 += pesum[(size_t)(p + 0) * (KB_NUM * DIMC) + j];
        e1 += pesum[(size_t)(p + 1) * (KB_NUM * DIMC) + j];
        e2 += pesum[(size_t)(p + 2) * (KB_NUM * DIMC) + j];
        e3 += pesum[(size_t)(p + 3) * (KB_NUM * DIMC) + j];
    }
    for (; p < P; ++p) e0 += pesum[(size_t)p * (KB_NUM * DIMC) + j];
    float es = (e0 + e1) + (e2 + e3);

    float nea = embed_avg[j] * DECAY_F + (1.0f - DECAY_F) * es;
    out[NEA_OFF + j] = nea;

    float ncs  = out[NCS_OFF + k];
    float ntot = ntotp[0];
    float denom = (ncs + EPS_F) / (ntot + (float)KB_NUM * EPS_F) * ntot;
    out[NEMB_OFF + j] = nea / denom;
}

// ---------------------------------------------------------------------------
extern "C" void kernel_launch(void* const* d_in, const int* in_sizes, int n_in,
                              void* d_out, int out_size, void* d_ws, size_t ws_size,
                              hipStream_t stream)
{
    const float* z            = (const float*)d_in[0];
    const float* emb          = (const float*)d_in[1];
    const float* cluster_size = (const float*)d_in[2];
    const float* embed_avg    = (const float*)d_in[3];
    float* out = (float*)d_out;

    char* ws = (char*)d_ws;
    float*     lossAcc = (float*)ws;                 // 1 f32
    float*     ntotp   = (float*)(ws + 64);          // 1 f32
    float*     enorm   = (float*)(ws + 256);         // 512 f32
    _Float16*  efrag   = (_Float16*)(ws + 4096);     // 128 KB
    const size_t PART_OFF   = 4096 + 131072;         // 135168
    const size_t pcnt_bytes  = (size_t)NPART * KB_NUM * sizeof(float);        // 512 KB
    const size_t pesum_bytes = (size_t)NPART * KB_NUM * DIMC * sizeof(float); // 32 MB
    const size_t need = PART_OFF + pcnt_bytes + pesum_bytes;   // ~32.7 MB

    int P;
    float *pcnt, *pesum;
    if (ws_size >= need) {
        P = NPART;
        pcnt  = (float*)(ws + PART_OFF);
        pesum = (float*)(ws + PART_OFF + pcnt_bytes);
        // partials fully overwritten by bin -> only zero the header
        hipMemsetAsync(ws, 0, 4096, stream);
    } else {
        P = 1;
        pcnt  = (float*)(ws + PART_OFF);
        pesum = (float*)(ws + PART_OFF + KB_NUM * sizeof(float));
        hipMemsetAsync(ws, 0, PART_OFF + (KB_NUM + KB_NUM * DIMC) * sizeof(float),
                       stream);
    }

    vq_prep_e<<<dim3(KB_NUM), dim3(DIMC), 0, stream>>>(emb, efrag, enorm);

    vq_main_kernel<<<dim3(NTOK / 256), dim3(256), 0, stream>>>(
        z, emb, efrag, enorm, out, lossAcc);

    if (P == NPART)
        vq_bin_kernel<false><<<dim3(NTOK / 512), dim3(512), 0, stream>>>(
            z, out, pcnt, pesum);
    else
        vq_bin_kernel<true><<<dim3(NTOK / 512), dim3(512), 0, stream>>>(
            z, out, pcnt, pesum);

    vq_stats_kernel<<<dim3(1), dim3(512), 0, stream>>>(
        cluster_size, pcnt, lossAcc, out, ntotp, P);

    vq_embed_kernel<<<dim3(KB_NUM * DIMC / 256), dim3(256), 0, stream>>>(
        embed_avg, pesum, ntotp, out, P);
}